// Round 11
// baseline (889.724 us; speedup 1.0000x reference)
//
#include <hip/hip_runtime.h>
#include <math.h>

#define B_ 64
#define T_ 1024
#define D_ 512
#define U_ 1024
#define NTILE 4

typedef __bf16 bf16x8 __attribute__((ext_vector_type(8)));
typedef float f32x16 __attribute__((ext_vector_type(16)));
typedef unsigned int u32;

// tanh(x) from x2l = 2x*log2(e), pre-clamped: 1 - 2/(1+2^{x2l}).
__device__ __forceinline__ float tanh_from_x2l(float x2l) {
    const float xc = __builtin_amdgcn_fmed3f(x2l, -26.f, 26.f);
    const float e  = exp2f(xc);
    const float r  = __builtin_amdgcn_rcpf(e + 1.0f);
    return fmaf(-2.0f, r, 1.0f);
}

// pack two f32 -> two bf16 (round-half-up): 2 adds + 1 v_perm
__device__ __forceinline__ u32 f2bf_pk(float lo, float hi) {
    u32 a = __float_as_uint(lo) + 0x8000u;
    u32 b = __float_as_uint(hi) + 0x8000u;
    return __builtin_amdgcn_perm(b, a, 0x07060302u);
}

// K_prep (2560 blocks):
//  [0,2048): feat fp32 -> featF bf16 in per-32-row-tile LDS-IMAGE order.
//    Tile bx covers feat rows [bx*32, bx*32+32). Image slot d (16 B units,
//    0..2047): d = p*128 + r*4 + qq with p=panel(kt), r=row, qq=q^xr,
//    xr=(r>>2)&3; content = bf16 of feat[row, s*8..s*8+8), s=p*4+q.
//    This is byte-for-byte the LDS layout logits' computeStep reads, so
//    logits staging becomes a RAW contiguous copy (no regs, no VALU).
//  [2048,2304): W1 -> W1F in MFMA B-fragment order (as before).
//  [2304,2560): ph[b][u] = hidden·W2 + W2_b + W1_b.
__global__ __launch_bounds__(256) void prep_kernel(
    const float* __restrict__ feat, const float* __restrict__ W1,
    const float* __restrict__ hidden, const float* __restrict__ W2,
    const float* __restrict__ W2b, const float* __restrict__ W1b,
    unsigned short* __restrict__ featF, unsigned short* __restrict__ W1F,
    float* __restrict__ ph) {
    const int bx  = blockIdx.x;
    const int tid = threadIdx.x;
    if (bx < 2048) {
        const float* src = feat + (size_t)bx * 32 * D_;
        char* dst = (char*)featF + (size_t)bx * 32768;
#pragma unroll
        for (int c = 0; c < 8; ++c) {
            const int d  = c * 256 + tid;      // 16B-slot index
            const int p  = d >> 7;
            const int r  = (d >> 2) & 31;
            const int qq = d & 3;
            const int q  = qq ^ ((r >> 2) & 3);
            const int s  = p * 4 + q;
            const float4 v0 = *(const float4*)(src + (size_t)r * D_ + s * 8);
            const float4 v1 = *(const float4*)(src + (size_t)r * D_ + s * 8 + 4);
            uint4 w;
            w.x = f2bf_pk(v0.x, v0.y);
            w.y = f2bf_pk(v0.z, v0.w);
            w.z = f2bf_pk(v1.x, v1.y);
            w.w = f2bf_pk(v1.z, v1.w);
            *(uint4*)(dst + (size_t)d * 16) = w;
        }
    } else if (bx < 2304) {
        const int gid  = (bx - 2048) * 256 + tid;  // 0..65535
        const int lane = gid & 63;
        const int frag = gid >> 6;
        const int ks = frag & 1;
        const int kt = (frag >> 1) & 15;
        const int ut = frag >> 5;
        const int u  = ut * 32 + (lane & 31);
        const int k0 = kt * 32 + ks * 16 + (lane >> 5) * 8;
        float f[8];
#pragma unroll
        for (int j = 0; j < 8; ++j) f[j] = W1[(size_t)(k0 + j) * U_ + u];
        uint4 w;
        w.x = f2bf_pk(f[0], f[1]);
        w.y = f2bf_pk(f[2], f[3]);
        w.z = f2bf_pk(f[4], f[5]);
        w.w = f2bf_pk(f[6], f[7]);
        *(uint4*)&W1F[(size_t)gid * 8] = w;
    } else {
        const int b2 = bx - 2304;
        const int u  = (b2 & 3) * 256 + tid;
        const int b  = b2 >> 2;
        const float* h = hidden + b * D_;
        float acc = 0.f;
#pragma unroll 8
        for (int d = 0; d < D_; ++d) acc = fmaf(h[d], W2[(size_t)d * U_ + u], acc);
        ph[b * U_ + u] = acc + W2b[u] + W1b[u];
    }
}

// K2: fused bf16 32x32x16-MFMA GEMM + tanh + V-dot, cross-tile pipelined.
// v11: the pipeline theory survived r8/r10; its REGISTER COST did not (arch
// VGPR ceiling = 128 for this family; r9 base = 120). Fix: A-conversion and
// swizzle moved to prep (featF = per-tile LDS byte image), so staging here is
// a raw contiguous 32 KB copy: per thread per quarter-chunk 2 uint4 loads +
// 2 ds_write_b128 (sr = 8 VGPR, zero VALU). Structure: 1024 blocks (gx =
// uh + 2*tg, tg owns 128 t), 4 waves x 32t x 128u, NTILE=4 tiles, As[2]
// ping-pong, ONE barrier per tile. b0f is always older than a chunk's stage
// loads in the vmcnt FIFO, so B-frag waits don't drain them; stage loads are
// consumed ~4 computeSteps after issue. Spill sentinel: WRITE_SIZE > 10 MB.
__global__ __launch_bounds__(256, 2) void logits_mfma_kernel(
    const unsigned short* __restrict__ featF,  // per-tile LDS images
    const unsigned short* __restrict__ W1F,    // fragment-order bf16
    const float* __restrict__ ph,              // [B,U] biases folded
    const float* __restrict__ Vw,              // [U]
    float* __restrict__ lpart) {               // [8][B][T] partials
    __shared__ __align__(16) char As[2][32768];

    const int tid  = threadIdx.x;
    const int gx   = blockIdx.x;        // uh fastest: A-sharing pair co-dispatch
    const int uh   = gx & 1;
    const int tg   = gx >> 1;           // 0..7 (128-t group)
    const int b    = blockIdx.y;
    const int lane = tid & 63;
    const int widx = tid >> 6;          // 0..3
    const int l31 = lane & 31, g = lane >> 5;

    const char* atb = (const char*)featF + ((size_t)b * 32 + tg * NTILE) * 32768;
    const char* bfbase = (const char*)W1F +
                         (size_t)(uh * 16 + widx * 4) * 32768 + lane * 16;

    // biases/V preloaded once (same u's for every tile); log2e folded
    float phv2[4], vwv[4];
#pragma unroll
    for (int nt = 0; nt < 4; ++nt) {
        const int u = uh * 512 + widx * 128 + nt * 32 + l31;
        phv2[nt] = 2.8853900817779268f * ph[b * U_ + u];  // 2*log2e*ph
        vwv[nt]  = Vw[u];
    }

    uint4 sr0, sr1;   // staging regs: ONE quarter-chunk = 32 B/thread
    auto issueA = [&](int i, int c) {
        const char* p = atb + (size_t)i * 32768 + c * 8192 + tid * 32;
        sr0 = *(const uint4*)p;
        sr1 = *(const uint4*)(p + 16);
    };
    auto writeA = [&](int i, int c) {
        char* d = As[i & 1] + c * 8192 + tid * 32;
        *(uint4*)d = sr0;
        *(uint4*)(d + 16) = sr1;
    };

    f32x16 acc[4];
    bf16x8 b0f[8], b1f[8];
    auto loadB = [&](bf16x8* dst, int kt) {
#pragma unroll
        for (int nt = 0; nt < 4; ++nt)
#pragma unroll
            for (int ks = 0; ks < 2; ++ks)
                dst[nt * 2 + ks] =
                    *(const bf16x8*)(bfbase + nt * 32768 + (kt * 2 + ks) * 1024);
    };
    auto computeStep = [&](const char* abuf, int kt, const bf16x8* bfr) {
        bf16x8 af[2];
#pragma unroll
        for (int ks = 0; ks < 2; ++ks) {
            const int q = (2 * ks + g) ^ ((l31 >> 2) & 3);
            af[ks] = *(const bf16x8*)&abuf[kt * 2048 + l31 * 64 + q * 16];
        }
        __builtin_amdgcn_s_setprio(1);
#pragma unroll
        for (int ks = 0; ks < 2; ++ks)
#pragma unroll
            for (int nt = 0; nt < 4; ++nt)
                acc[nt] = __builtin_amdgcn_mfma_f32_32x32x16_bf16(
                    af[ks], bfr[nt * 2 + ks], acc[nt], 0, 0, 0);
        __builtin_amdgcn_s_setprio(0);
    };

#pragma unroll
    for (int nt = 0; nt < 4; ++nt) acc[nt] = (f32x16)(0.f);

    // prologue: stage tile 0 fully (raw copy), then the per-tile barrier
#pragma unroll
    for (int c = 0; c < 4; ++c) { issueA(0, c); writeA(0, c); }
    __syncthreads();

    for (int i = 0; i < NTILE; ++i) {
        const char* abuf = As[i & 1];
        const bool pf = (i + 1 < NTILE);

        loadB(b0f, 0);
#pragma unroll
        for (int grp = 0; grp < 4; ++grp) {
            const int kt = grp * 4;
            if (pf) issueA(i + 1, grp);    // 32 B/thread fly over this group
            loadB(b1f, kt + 1);
            computeStep(abuf, kt, b0f);
            loadB(b0f, kt + 2);
            computeStep(abuf, kt + 1, b1f);
            loadB(b1f, kt + 3);
            computeStep(abuf, kt + 2, b0f);
            if (kt + 4 < 16) loadB(b0f, kt + 4);
            computeStep(abuf, kt + 3, b1f);
            if (pf) writeA(i + 1, grp);    // consumed ~4 steps after issue
        }

        // ---- epilogue tile i: tanh + V-dot into v[16] ----
        float v[16];
#pragma unroll
        for (int k = 0; k < 16; ++k) v[k] = 0.f;
#pragma unroll
        for (int nt = 0; nt < 4; ++nt)
#pragma unroll
            for (int rr = 0; rr < 16; ++rr)
                v[rr] = fmaf(
                    vwv[nt],
                    tanh_from_x2l(fmaf(2.8853900817779268f, acc[nt][rr],
                                       phv2[nt])),
                    v[rr]);
#pragma unroll
        for (int nt = 0; nt < 4; ++nt) acc[nt] = (f32x16)(0.f);

        // multi-value tree over the 16-lane groups; butterfly pb=16 completes.
#pragma unroll
        for (int st = 0; st < 4; ++st) {
            const int pb = 1 << st;
            const bool hi = (l31 & pb) != 0;
#pragma unroll
            for (int j = 0; j < (8 >> st); ++j) {
                const float a = v[2 * j];
                const float c = v[2 * j + 1];
                const float keep = hi ? c : a;
                const float send = hi ? a : c;
                v[j] = keep + __shfl_xor(send, pb);
            }
        }
        v[0] += __shfl_xor(v[0], 16);

        // identity-order gather + one ascending-contiguous 128 B store/wave.
        const int srcl = ((lane & 3) | (((lane >> 3) & 3) << 2)) +
                         32 * ((lane >> 2) & 1);
        const float out = __shfl(v[0], srcl);
        if (lane < 32)
            lpart[(size_t)(uh * 4 + widx) * (B_ * T_) + (size_t)b * T_ +
                  tg * 128 + i * 32 + lane] = out;
        __syncthreads();   // tile i reads done; As[(i+1)&1] writes visible
    }
}

// K3: fused softmax + attn-write + context, ATOMIC-FREE (r9's proven form).
__global__ __launch_bounds__(512) void ctx_kernel(
    const float* __restrict__ feat, const float* __restrict__ lpart,
    float* __restrict__ attn, float* __restrict__ ctx_out) {
    const int b   = blockIdx.y;
    const int ds  = blockIdx.x;     // 0..7: 64-d slice
    const int tid = threadIdx.x;
    __shared__ float wls[1024];
    __shared__ float redm[8];
    __shared__ float reds[8];
    __shared__ float cpart[8][64];

    float v[2];
    float mx = -3.4e38f;
#pragma unroll
    for (int j = 0; j < 2; ++j) {
        const int t = b * T_ + tid + 512 * j;
        float s0 = 0.f, s1 = 0.f;
#pragma unroll
        for (int sl = 0; sl < 4; ++sl) {
            s0 += lpart[(size_t)(2 * sl) * (B_ * T_) + t];
            s1 += lpart[(size_t)(2 * sl + 1) * (B_ * T_) + t];
        }
        v[j] = s0 + s1;
        mx = fmaxf(mx, v[j]);
    }
#pragma unroll
    for (int off = 32; off > 0; off >>= 1) mx = fmaxf(mx, __shfl_xor(mx, off));
    if ((tid & 63) == 0) redm[tid >> 6] = mx;
    __syncthreads();
    mx = fmaxf(fmaxf(fmaxf(redm[0], redm[1]), fmaxf(redm[2], redm[3])),
               fmaxf(fmaxf(redm[4], redm[5]), fmaxf(redm[6], redm[7])));
    float s = 0.f;
#pragma unroll
    for (int j = 0; j < 2; ++j) {
        v[j] = __expf(v[j] - mx);
        s += v[j];
    }
#pragma unroll
    for (int off = 32; off > 0; off >>= 1) s += __shfl_xor(s, off);
    if ((tid & 63) == 0) reds[tid >> 6] = s;
    __syncthreads();
    s = ((reds[0] + reds[1]) + (reds[2] + reds[3])) +
        ((reds[4] + reds[5]) + (reds[6] + reds[7]));
    const float inv = 1.0f / s;
    wls[tid]       = v[0] * inv;
    wls[tid + 512] = v[1] * inv;
    __syncthreads();

    if (ds == 0) {
        attn[b * T_ + tid]       = wls[tid];
        attn[b * T_ + tid + 512] = wls[tid + 512];
    }

    const int tc = tid >> 6;        // 0..7
    const int dl = tid & 63;
    const float* fb =
        feat + ((size_t)(b * T_ + tc * 128)) * D_ + ds * 64 + dl;
    const float* wb = &wls[tc * 128];
    float acc = 0.f;
#pragma unroll 4
    for (int t = 0; t < 128; ++t)
        acc = fmaf(wb[t], fb[(size_t)t * D_], acc);
    cpart[tc][dl] = acc;
    __syncthreads();
    if (tid < 64) {
        float cs = 0.f;
#pragma unroll
        for (int k = 0; k < 8; ++k) cs += cpart[k][tid];
        ctx_out[b * D_ + ds * 64 + tid] = cs;
    }
}

extern "C" void kernel_launch(void* const* d_in, const int* in_sizes, int n_in,
                              void* d_out, int out_size, void* d_ws, size_t ws_size,
                              hipStream_t stream) {
    const float* feat   = (const float*)d_in[0];
    const float* hidden = (const float*)d_in[1];
    const float* W1w    = (const float*)d_in[2];
    const float* W1b    = (const float*)d_in[3];
    const float* W2w    = (const float*)d_in[4];
    const float* W2b    = (const float*)d_in[5];
    const float* Vw     = (const float*)d_in[6];
    // V_b cancels in softmax and doesn't affect context.

    float* out_ctx  = (float*)d_out;             // [B,D]
    float* out_attn = out_ctx + B_ * D_;         // [B,T]

    // workspace: featF (64 MB) | W1F (1 MB) | ph (256 KB) | lpart (2 MB)
    unsigned short* featF = (unsigned short*)d_ws;
    unsigned short* W1F   = featF + (size_t)B_ * T_ * D_;
    float* ph    = (float*)(W1F + (size_t)U_ * D_);
    float* lpart = ph + B_ * U_;

    prep_kernel<<<2560, 256, 0, stream>>>(feat, W1w, hidden, W2w, W2b, W1b,
                                          featF, W1F, ph);
    logits_mfma_kernel<<<dim3(16, B_), 256, 0, stream>>>(featF, W1F, ph, Vw,
                                                         lpart);
    ctx_kernel<<<dim3(8, B_), 512, 0, stream>>>(feat, lpart, out_attn, out_ctx);
}

// Round 12
// 879.538 us; speedup vs baseline: 1.0116x; 1.0116x over previous
//
#include <hip/hip_runtime.h>
#include <math.h>

#define B_ 64
#define T_ 1024
#define D_ 512
#define U_ 1024
#define NTILE 4

typedef __bf16 bf16x8 __attribute__((ext_vector_type(8)));
typedef float f32x16 __attribute__((ext_vector_type(16)));
typedef unsigned int u32;

// global -> LDS DMA, 16 B per lane, zero VGPR round-trip. LDS dest must be
// wave-uniform; HW adds lane*16. (m97 pattern; featF is pre-swizzled so the
// LDS image is linear — m173's "pre-swizzled global + linear LDS".)
__device__ __forceinline__ void gl_lds16(const void* g, void* l) {
    __builtin_amdgcn_global_load_lds(
        (const __attribute__((address_space(1))) void*)g,
        (__attribute__((address_space(3))) void*)l, 16, 0, 0);
}

// tanh(x) from x2l = 2x*log2(e), pre-clamped: 1 - 2/(1+2^{x2l}).
__device__ __forceinline__ float tanh_from_x2l(float x2l) {
    const float xc = __builtin_amdgcn_fmed3f(x2l, -26.f, 26.f);
    const float e  = exp2f(xc);
    const float r  = __builtin_amdgcn_rcpf(e + 1.0f);
    return fmaf(-2.0f, r, 1.0f);
}

// pack two f32 -> two bf16 (round-half-up): 2 adds + 1 v_perm
__device__ __forceinline__ u32 f2bf_pk(float lo, float hi) {
    u32 a = __float_as_uint(lo) + 0x8000u;
    u32 b = __float_as_uint(hi) + 0x8000u;
    return __builtin_amdgcn_perm(b, a, 0x07060302u);
}

// K_prep (2560 blocks):
//  [0,2048): feat fp32 -> featF bf16 in per-32-row-tile LDS-IMAGE order.
//    Tile bx covers feat rows [bx*32, bx*32+32). Slot d (16 B units): d =
//    p*128 + r*4 + qq, qq = q^((r>>2)&3), content = bf16 of
//    feat[row, (p*4+q)*8 ..+8). Byte-for-byte the LDS layout logits reads,
//    so logits staging is a RAW contiguous copy (DMA-able, no regs).
//  [2048,2304): W1 -> W1F in MFMA B-fragment order.
//  [2304,2560): ph[b][u] = hidden·W2 + W2_b + W1_b.
__global__ __launch_bounds__(256) void prep_kernel(
    const float* __restrict__ feat, const float* __restrict__ W1,
    const float* __restrict__ hidden, const float* __restrict__ W2,
    const float* __restrict__ W2b, const float* __restrict__ W1b,
    unsigned short* __restrict__ featF, unsigned short* __restrict__ W1F,
    float* __restrict__ ph) {
    const int bx  = blockIdx.x;
    const int tid = threadIdx.x;
    if (bx < 2048) {
        const float* src = feat + (size_t)bx * 32 * D_;
        char* dst = (char*)featF + (size_t)bx * 32768;
#pragma unroll
        for (int c = 0; c < 8; ++c) {
            const int d  = c * 256 + tid;      // 16B-slot index
            const int p  = d >> 7;
            const int r  = (d >> 2) & 31;
            const int qq = d & 3;
            const int q  = qq ^ ((r >> 2) & 3);
            const int s  = p * 4 + q;
            const float4 v0 = *(const float4*)(src + (size_t)r * D_ + s * 8);
            const float4 v1 = *(const float4*)(src + (size_t)r * D_ + s * 8 + 4);
            uint4 w;
            w.x = f2bf_pk(v0.x, v0.y);
            w.y = f2bf_pk(v0.z, v0.w);
            w.z = f2bf_pk(v1.x, v1.y);
            w.w = f2bf_pk(v1.z, v1.w);
            *(uint4*)(dst + (size_t)d * 16) = w;
        }
    } else if (bx < 2304) {
        const int gid  = (bx - 2048) * 256 + tid;  // 0..65535
        const int lane = gid & 63;
        const int frag = gid >> 6;
        const int ks = frag & 1;
        const int kt = (frag >> 1) & 15;
        const int ut = frag >> 5;
        const int u  = ut * 32 + (lane & 31);
        const int k0 = kt * 32 + ks * 16 + (lane >> 5) * 8;
        float f[8];
#pragma unroll
        for (int j = 0; j < 8; ++j) f[j] = W1[(size_t)(k0 + j) * U_ + u];
        uint4 w;
        w.x = f2bf_pk(f[0], f[1]);
        w.y = f2bf_pk(f[2], f[3]);
        w.z = f2bf_pk(f[4], f[5]);
        w.w = f2bf_pk(f[6], f[7]);
        *(uint4*)&W1F[(size_t)gid * 8] = w;
    } else {
        const int b2 = bx - 2304;
        const int u  = (b2 & 3) * 256 + tid;
        const int b  = b2 >> 2;
        const float* h = hidden + b * D_;
        float acc = 0.f;
#pragma unroll 8
        for (int d = 0; d < D_; ++d) acc = fmaf(h[d], W2[(size_t)d * U_ + u], acc);
        ph[b * U_ + u] = acc + W2b[u] + W1b[u];
    }
}

// K2: fused bf16 32x32x16-MFMA GEMM + tanh + V-dot, cross-tile pipelined via
// global_load_lds DMA (v13). Register law established r3/r8/r10/r11: with
// acc's 64 AGPRs live, this family's arch-VGPR cap is 128 and the base
// K-loop uses 120 — register-staged pipelines ALWAYS spill. global_load_lds
// stages with ZERO VGPRs: featF is the byte-exact LDS image, so each wave
// issues 8 x 16B-per-lane DMA calls (1 KB each) for its 8 KB tile segment,
// 2 at the END of each kt-group (after that group's loadBs -> no B-frag wait
// ever drains a DMA; only the per-tile __syncthreads does, a full group +
// epilogue after issue). Structure otherwise r11: 1024 blocks, 4 waves x
// 32t x 128u, NTILE=4, As[2] ping-pong, ONE barrier per tile.
// Sentinels: VGPR_Count <= 126, WRITE_SIZE ~2 MB.
__global__ __launch_bounds__(256, 2) void logits_mfma_kernel(
    const unsigned short* __restrict__ featF,  // per-tile LDS images
    const unsigned short* __restrict__ W1F,    // fragment-order bf16
    const float* __restrict__ ph,              // [B,U] biases folded
    const float* __restrict__ Vw,              // [U]
    float* __restrict__ lpart) {               // [8][B][T] partials
    __shared__ __align__(16) char As[2][32768];

    const int tid  = threadIdx.x;
    const int gx   = blockIdx.x;        // uh fastest: A-sharing pair co-dispatch
    const int uh   = gx & 1;
    const int tg   = gx >> 1;           // 0..7 (128-t group)
    const int b    = blockIdx.y;
    const int lane = tid & 63;
    const int widx = tid >> 6;          // 0..3
    const int l31 = lane & 31, g = lane >> 5;

    // wave's global source base for staging: lane's 16 B within the wave's
    // 8 KB segment of the 32 KB tile image.
    const char* atb = (const char*)featF + ((size_t)b * 32 + tg * NTILE) * 32768 +
                      widx * 8192 + (lane << 4);
    const char* bfbase = (const char*)W1F +
                         (size_t)(uh * 16 + widx * 4) * 32768 + lane * 16;

    // biases/V preloaded once (same u's for every tile); log2e folded
    float phv2[4], vwv[4];
#pragma unroll
    for (int nt = 0; nt < 4; ++nt) {
        const int u = uh * 512 + widx * 128 + nt * 32 + l31;
        phv2[nt] = 2.8853900817779268f * ph[b * U_ + u];  // 2*log2e*ph
        vwv[nt]  = Vw[u];
    }

    // DMA one 2 KB sub-segment (2 calls x 1 KB) of tile i's wave segment.
    auto stageA = [&](int i, int c) {
        const char* gsrc = atb + (size_t)i * 32768 + c * 2048;
        char* ldst = As[i & 1] + widx * 8192 + c * 2048;
        gl_lds16(gsrc, ldst);
        gl_lds16(gsrc + 1024, ldst + 1024);
    };

    f32x16 acc[4];
    bf16x8 b0f[8], b1f[8];
    auto loadB = [&](bf16x8* dst, int kt) {
#pragma unroll
        for (int nt = 0; nt < 4; ++nt)
#pragma unroll
            for (int ks = 0; ks < 2; ++ks)
                dst[nt * 2 + ks] =
                    *(const bf16x8*)(bfbase + nt * 32768 + (kt * 2 + ks) * 1024);
    };
    auto computeStep = [&](const char* abuf, int kt, const bf16x8* bfr) {
        bf16x8 af[2];
#pragma unroll
        for (int ks = 0; ks < 2; ++ks) {
            const int q = (2 * ks + g) ^ ((l31 >> 2) & 3);
            af[ks] = *(const bf16x8*)&abuf[kt * 2048 + l31 * 64 + q * 16];
        }
        __builtin_amdgcn_s_setprio(1);
#pragma unroll
        for (int ks = 0; ks < 2; ++ks)
#pragma unroll
            for (int nt = 0; nt < 4; ++nt)
                acc[nt] = __builtin_amdgcn_mfma_f32_32x32x16_bf16(
                    af[ks], bfr[nt * 2 + ks], acc[nt], 0, 0, 0);
        __builtin_amdgcn_s_setprio(0);
    };

#pragma unroll
    for (int nt = 0; nt < 4; ++nt) acc[nt] = (f32x16)(0.f);

    // prologue: DMA tile 0 fully; __syncthreads drains vmcnt -> LDS valid
#pragma unroll
    for (int c = 0; c < 4; ++c) stageA(0, c);
    __syncthreads();

    for (int i = 0; i < NTILE; ++i) {
        const char* abuf = As[i & 1];
        const bool pf = (i + 1 < NTILE);

        loadB(b0f, 0);
#pragma unroll
        for (int grp = 0; grp < 4; ++grp) {
            const int kt = grp * 4;
            loadB(b1f, kt + 1);
            computeStep(abuf, kt, b0f);
            loadB(b0f, kt + 2);
            computeStep(abuf, kt + 1, b1f);
            loadB(b1f, kt + 3);
            computeStep(abuf, kt + 2, b0f);
            if (kt + 4 < 16) loadB(b0f, kt + 4);
            computeStep(abuf, kt + 3, b1f);
            if (pf) stageA(i + 1, grp);   // DMA after this grp's loadBs:
                                          // nothing waits on it but the barrier
        }

        // ---- epilogue tile i: tanh + V-dot into v[16] ----
        float v[16];
#pragma unroll
        for (int k = 0; k < 16; ++k) v[k] = 0.f;
#pragma unroll
        for (int nt = 0; nt < 4; ++nt)
#pragma unroll
            for (int rr = 0; rr < 16; ++rr)
                v[rr] = fmaf(
                    vwv[nt],
                    tanh_from_x2l(fmaf(2.8853900817779268f, acc[nt][rr],
                                       phv2[nt])),
                    v[rr]);
#pragma unroll
        for (int nt = 0; nt < 4; ++nt) acc[nt] = (f32x16)(0.f);

        // multi-value tree over the 16-lane groups; butterfly pb=16 completes.
#pragma unroll
        for (int st = 0; st < 4; ++st) {
            const int pb = 1 << st;
            const bool hi = (l31 & pb) != 0;
#pragma unroll
            for (int j = 0; j < (8 >> st); ++j) {
                const float a = v[2 * j];
                const float c = v[2 * j + 1];
                const float keep = hi ? c : a;
                const float send = hi ? a : c;
                v[j] = keep + __shfl_xor(send, pb);
            }
        }
        v[0] += __shfl_xor(v[0], 16);

        // identity-order gather + one ascending-contiguous 128 B store/wave.
        const int srcl = ((lane & 3) | (((lane >> 3) & 3) << 2)) +
                         32 * ((lane >> 2) & 1);
        const float out = __shfl(v[0], srcl);
        if (lane < 32)
            lpart[(size_t)(uh * 4 + widx) * (B_ * T_) + (size_t)b * T_ +
                  tg * 128 + i * 32 + lane] = out;
        __syncthreads();   // drains DMA for tile i+1; As[(i+1)&1] now valid
    }
}

// K3: fused softmax + attn-write + context, ATOMIC-FREE (r9's proven form).
__global__ __launch_bounds__(512) void ctx_kernel(
    const float* __restrict__ feat, const float* __restrict__ lpart,
    float* __restrict__ attn, float* __restrict__ ctx_out) {
    const int b   = blockIdx.y;
    const int ds  = blockIdx.x;     // 0..7: 64-d slice
    const int tid = threadIdx.x;
    __shared__ float wls[1024];
    __shared__ float redm[8];
    __shared__ float reds[8];
    __shared__ float cpart[8][64];

    float v[2];
    float mx = -3.4e38f;
#pragma unroll
    for (int j = 0; j < 2; ++j) {
        const int t = b * T_ + tid + 512 * j;
        float s0 = 0.f, s1 = 0.f;
#pragma unroll
        for (int sl = 0; sl < 4; ++sl) {
            s0 += lpart[(size_t)(2 * sl) * (B_ * T_) + t];
            s1 += lpart[(size_t)(2 * sl + 1) * (B_ * T_) + t];
        }
        v[j] = s0 + s1;
        mx = fmaxf(mx, v[j]);
    }
#pragma unroll
    for (int off = 32; off > 0; off >>= 1) mx = fmaxf(mx, __shfl_xor(mx, off));
    if ((tid & 63) == 0) redm[tid >> 6] = mx;
    __syncthreads();
    mx = fmaxf(fmaxf(fmaxf(redm[0], redm[1]), fmaxf(redm[2], redm[3])),
               fmaxf(fmaxf(redm[4], redm[5]), fmaxf(redm[6], redm[7])));
    float s = 0.f;
#pragma unroll
    for (int j = 0; j < 2; ++j) {
        v[j] = __expf(v[j] - mx);
        s += v[j];
    }
#pragma unroll
    for (int off = 32; off > 0; off >>= 1) s += __shfl_xor(s, off);
    if ((tid & 63) == 0) reds[tid >> 6] = s;
    __syncthreads();
    s = ((reds[0] + reds[1]) + (reds[2] + reds[3])) +
        ((reds[4] + reds[5]) + (reds[6] + reds[7]));
    const float inv = 1.0f / s;
    wls[tid]       = v[0] * inv;
    wls[tid + 512] = v[1] * inv;
    __syncthreads();

    if (ds == 0) {
        attn[b * T_ + tid]       = wls[tid];
        attn[b * T_ + tid + 512] = wls[tid + 512];
    }

    const int tc = tid >> 6;        // 0..7
    const int dl = tid & 63;
    const float* fb =
        feat + ((size_t)(b * T_ + tc * 128)) * D_ + ds * 64 + dl;
    const float* wb = &wls[tc * 128];
    float acc = 0.f;
#pragma unroll 4
    for (int t = 0; t < 128; ++t)
        acc = fmaf(wb[t], fb[(size_t)t * D_], acc);
    cpart[tc][dl] = acc;
    __syncthreads();
    if (tid < 64) {
        float cs = 0.f;
#pragma unroll
        for (int k = 0; k < 8; ++k) cs += cpart[k][tid];
        ctx_out[b * D_ + ds * 64 + tid] = cs;
    }
}

extern "C" void kernel_launch(void* const* d_in, const int* in_sizes, int n_in,
                              void* d_out, int out_size, void* d_ws, size_t ws_size,
                              hipStream_t stream) {
    const float* feat   = (const float*)d_in[0];
    const float* hidden = (const float*)d_in[1];
    const float* W1w    = (const float*)d_in[2];
    const float* W1b    = (const float*)d_in[3];
    const float* W2w    = (const float*)d_in[4];
    const float* W2b    = (const float*)d_in[5];
    const float* Vw     = (const float*)d_in[6];
    // V_b cancels in softmax and doesn't affect context.

    float* out_ctx  = (float*)d_out;             // [B,D]
    float* out_attn = out_ctx + B_ * D_;         // [B,T]

    // workspace: featF (64 MB) | W1F (1 MB) | ph (256 KB) | lpart (2 MB)
    unsigned short* featF = (unsigned short*)d_ws;
    unsigned short* W1F   = featF + (size_t)B_ * T_ * D_;
    float* ph    = (float*)(W1F + (size_t)U_ * D_);
    float* lpart = ph + B_ * U_;

    prep_kernel<<<2560, 256, 0, stream>>>(feat, W1w, hidden, W2w, W2b, W1b,
                                          featF, W1F, ph);
    logits_mfma_kernel<<<dim3(16, B_), 256, 0, stream>>>(featF, W1F, ph, Vw,
                                                         lpart);
    ctx_kernel<<<dim3(8, B_), 512, 0, stream>>>(feat, lpart, out_attn, out_ctx);
}

// Round 13
// 567.340 us; speedup vs baseline: 1.5682x; 1.5503x over previous
//
#include <hip/hip_runtime.h>
#include <math.h>

#define B_ 64
#define T_ 1024
#define D_ 512
#define U_ 1024

typedef __bf16 bf16x8 __attribute__((ext_vector_type(8)));
typedef float f32x16 __attribute__((ext_vector_type(16)));
typedef unsigned int u32;

// tanh(x) from x2l = 2x*log2(e), pre-clamped: 1 - 2/(1+2^{x2l}).
__device__ __forceinline__ float tanh_from_x2l(float x2l) {
    const float xc = __builtin_amdgcn_fmed3f(x2l, -26.f, 26.f);
    const float e  = exp2f(xc);
    const float r  = __builtin_amdgcn_rcpf(e + 1.0f);
    return fmaf(-2.0f, r, 1.0f);
}

// pack two f32 -> two bf16 (round-half-up): 2 adds + 1 v_perm
__device__ __forceinline__ u32 f2bf_pk(float lo, float hi) {
    u32 a = __float_as_uint(lo) + 0x8000u;
    u32 b = __float_as_uint(hi) + 0x8000u;
    return __builtin_amdgcn_perm(b, a, 0x07060302u);
}

// K_prep: blocks [0,256): W1 [D][U] fp32 -> W1F in MFMA B-fragment order:
//   frag=(ut*16+kt)*2+ks holds B-frag for u-tile ut (32 u), k=kt*32+ks*16;
//   slot (frag,lane) = 8 bf16: u=ut*32+(lane&31), k0=kt*32+ks*16+(lane>>5)*8.
// blocks [256,512): ph[b][u] = hidden·W2 + W2_b + W1_b.
__global__ __launch_bounds__(256) void prep_kernel(
    const float* __restrict__ W1, const float* __restrict__ hidden,
    const float* __restrict__ W2, const float* __restrict__ W2b,
    const float* __restrict__ W1b,
    unsigned short* __restrict__ W1F, float* __restrict__ ph) {
    if (blockIdx.x < 256) {
        const int gid  = blockIdx.x * 256 + threadIdx.x;  // 0..65535
        const int lane = gid & 63;
        const int frag = gid >> 6;                        // 0..1023
        const int ks = frag & 1;
        const int kt = (frag >> 1) & 15;
        const int ut = frag >> 5;
        const int u  = ut * 32 + (lane & 31);
        const int k0 = kt * 32 + ks * 16 + (lane >> 5) * 8;
        float f[8];
#pragma unroll
        for (int j = 0; j < 8; ++j) f[j] = W1[(size_t)(k0 + j) * U_ + u];
        uint4 w;
        w.x = f2bf_pk(f[0], f[1]);
        w.y = f2bf_pk(f[2], f[3]);
        w.z = f2bf_pk(f[4], f[5]);
        w.w = f2bf_pk(f[6], f[7]);
        *(uint4*)&W1F[(size_t)gid * 8] = w;
    } else {
        const int bx = blockIdx.x - 256;
        const int u  = (bx & 3) * 256 + threadIdx.x;
        const int b  = bx >> 2;
        const float* h = hidden + b * D_;
        float acc = 0.f;
#pragma unroll 8
        for (int d = 0; d < D_; ++d) acc = fmaf(h[d], W2[(size_t)d * U_ + u], acc);
        ph[b * U_ + u] = acc + W2b[u] + W1b[u];
    }
}

// K2: fused bf16 32x32x16-MFMA GEMM + tanh + V-dot, v14: OCCUPANCY build.
// Post-mortem law (r8/r10/r11/v13): any multi-tile intra-block pipeline
// collapses the allocator (same 128-VGPR + scratch signature regardless of
// nominal liveness) — abandoned. Working variants (r6/r7/r9) all plateau at
// ~103 µs, Occupancy ~20% (8 waves/CU), nothing saturated: latency-bound
// with too few waves. v14 lever: 32-row tile + BOTH u-halves per block
// (512 thr, 8 waves x 32t x 128u) -> LDS 32 KB -> 4 blocks/CU = 32 waves/CU
// (4x r9). Each feat row staged ONCE (was twice). Single barrier; r9's
// proven K-loop/epilogue body (no mt dim); acc = 64 AGPR; no pipelining.
// Sentinels: VGPR <= 126, WRITE_SIZE ~2 MB.
__global__ __launch_bounds__(512, 4) void logits_mfma_kernel(
    const float* __restrict__ feat,          // [B,T,D] fp32
    const unsigned short* __restrict__ W1F,  // fragment-order bf16
    const float* __restrict__ ph,            // [B,U] biases folded
    const float* __restrict__ Vw,            // [U]
    float* __restrict__ lpart) {             // [8][B][T] partials
    __shared__ __align__(16) char As[32768];  // 16 panels x 32 rows x 64 B

    const int tid  = threadIdx.x;
    const int tt   = blockIdx.x;        // 0..31: 32-row t-tile
    const int b    = blockIdx.y;
    const int lane = tid & 63;
    const int widx = tid >> 6;          // 0..7: u-strip [widx*128, +128)
    const int l31 = lane & 31, g = lane >> 5;

    // biases/V preloaded once; log2e folded (issue before staging loads)
    float phv2[4], vwv[4];
#pragma unroll
    for (int nt = 0; nt < 4; ++nt) {
        const int u = widx * 128 + nt * 32 + l31;
        phv2[nt] = 2.8853900817779268f * ph[b * U_ + u];  // 2*log2e*ph
        vwv[nt]  = Vw[u];
    }

    // ---- stage A once: 32 rows x 512 d fp32 -> bf16 swizzled panels ----
    // 512 threads: 16 threads/row, 4 16B-slots each.
    {
        const int r  = tid >> 4;       // 0..31
        const int s0 = tid & 15;
        const int xr = (r >> 2) & 3;
        const float* src = feat + ((size_t)(b * T_ + tt * 32 + r)) * D_;
#pragma unroll
        for (int i = 0; i < 4; ++i) {
            const int s = s0 + 16 * i;           // 16B slot in row
            const float4 v0 = *(const float4*)(src + s * 8);
            const float4 v1 = *(const float4*)(src + s * 8 + 4);
            uint4 w;
            w.x = f2bf_pk(v0.x, v0.y);
            w.y = f2bf_pk(v0.z, v0.w);
            w.z = f2bf_pk(v1.x, v1.y);
            w.w = f2bf_pk(v1.z, v1.w);
            *(uint4*)&As[(s >> 2) * 2048 + r * 64 + ((s & 3) ^ xr) * 16] = w;
        }
    }
    __syncthreads();   // the ONLY barrier in this kernel

    // B frag base for the wave's u-strip: ut = widx*4 .. widx*4+3
    const char* bfbase = (const char*)W1F + (size_t)(widx * 4) * 32768 +
                         lane * 16;

    f32x16 acc[4];
    bf16x8 b0[8], b1[8];
    auto loadB = [&](bf16x8* dst, int kt) {
#pragma unroll
        for (int nt = 0; nt < 4; ++nt)
#pragma unroll
            for (int ks = 0; ks < 2; ++ks)
                dst[nt * 2 + ks] =
                    *(const bf16x8*)(bfbase + nt * 32768 + (kt * 2 + ks) * 1024);
    };
    auto computeStep = [&](int kt, const bf16x8* bfr) {
        bf16x8 af[2];
#pragma unroll
        for (int ks = 0; ks < 2; ++ks) {
            const int q = (2 * ks + g) ^ ((l31 >> 2) & 3);
            af[ks] = *(const bf16x8*)&As[kt * 2048 + l31 * 64 + q * 16];
        }
        __builtin_amdgcn_s_setprio(1);
#pragma unroll
        for (int ks = 0; ks < 2; ++ks)
#pragma unroll
            for (int nt = 0; nt < 4; ++nt)
                acc[nt] = __builtin_amdgcn_mfma_f32_32x32x16_bf16(
                    af[ks], bfr[nt * 2 + ks], acc[nt], 0, 0, 0);
        __builtin_amdgcn_s_setprio(0);
    };

#pragma unroll
    for (int nt = 0; nt < 4; ++nt) acc[nt] = (f32x16)(0.f);

    loadB(b0, 0);
    for (int kt = 0; kt < 16; kt += 2) {
        loadB(b1, kt + 1);
        computeStep(kt, b0);
        if (kt + 2 < 16) loadB(b0, kt + 2);
        computeStep(kt + 1, b1);
    }

    // ---- fused epilogue: tanh + V-dot into v[16] ----
    float v[16];
#pragma unroll
    for (int k = 0; k < 16; ++k) v[k] = 0.f;
#pragma unroll
    for (int nt = 0; nt < 4; ++nt)
#pragma unroll
        for (int rr = 0; rr < 16; ++rr)
            v[rr] = fmaf(
                vwv[nt],
                tanh_from_x2l(fmaf(2.8853900817779268f, acc[nt][rr], phv2[nt])),
                v[rr]);

    // multi-value tree over l31 bits 0..3 (16 values), then pb=16 butterfly:
    // lane p holds the full 64-lane... (both 32-col halves summed per row).
#pragma unroll
    for (int st = 0; st < 4; ++st) {
        const int pb = 1 << st;
        const bool hi = (l31 & pb) != 0;
#pragma unroll
        for (int j = 0; j < (8 >> st); ++j) {
            const float a = v[2 * j];
            const float c = v[2 * j + 1];
            const float keep = hi ? c : a;
            const float send = hi ? a : c;
            v[j] = keep + __shfl_xor(send, pb);
        }
    }
    v[0] += __shfl_xor(v[0], 16);
    // lane p (p<16 per half, both halves equal) holds t-row
    //   row(p,g) = (p&3) + 8*((p>>2)&3) + 4*g.

    // identity-order gather: dest lane d<32 wants src with p=(d&3)|((d>>3)<<2),
    // g=(d>>2)&1. One ascending-contiguous 128 B store per wave.
    const int srcl = ((lane & 3) | (((lane >> 3) & 3) << 2)) +
                     32 * ((lane >> 2) & 1);
    const float out = __shfl(v[0], srcl);
    if (lane < 32)
        lpart[(size_t)widx * (B_ * T_) + (size_t)b * T_ + tt * 32 + lane] = out;
}

// K3: fused softmax + attn-write + context, ATOMIC-FREE (r9's proven form).
// grid (8 ds, B): block (ds,b) owns d-slice [ds*64, ds*64+64) across ALL t,
// writes its ctx slice directly. Softmax stats recomputed per block (lpart
// row = 8 KB, L2-hot). Context: 8 t-chunks x 64 d lanes, coalesced 256 B
// reads, wls wave-uniform broadcast; LDS-reduce chunks; 64 threads store.
__global__ __launch_bounds__(512) void ctx_kernel(
    const float* __restrict__ feat, const float* __restrict__ lpart,
    float* __restrict__ attn, float* __restrict__ ctx_out) {
    const int b   = blockIdx.y;
    const int ds  = blockIdx.x;     // 0..7: 64-d slice
    const int tid = threadIdx.x;
    __shared__ float wls[1024];
    __shared__ float redm[8];
    __shared__ float reds[8];
    __shared__ float cpart[8][64];

    float v[2];
    float mx = -3.4e38f;
#pragma unroll
    for (int j = 0; j < 2; ++j) {
        const int t = b * T_ + tid + 512 * j;
        float s0 = 0.f, s1 = 0.f;
#pragma unroll
        for (int sl = 0; sl < 4; ++sl) {
            s0 += lpart[(size_t)(2 * sl) * (B_ * T_) + t];
            s1 += lpart[(size_t)(2 * sl + 1) * (B_ * T_) + t];
        }
        v[j] = s0 + s1;
        mx = fmaxf(mx, v[j]);
    }
#pragma unroll
    for (int off = 32; off > 0; off >>= 1) mx = fmaxf(mx, __shfl_xor(mx, off));
    if ((tid & 63) == 0) redm[tid >> 6] = mx;
    __syncthreads();
    mx = fmaxf(fmaxf(fmaxf(redm[0], redm[1]), fmaxf(redm[2], redm[3])),
               fmaxf(fmaxf(redm[4], redm[5]), fmaxf(redm[6], redm[7])));
    float s = 0.f;
#pragma unroll
    for (int j = 0; j < 2; ++j) {
        v[j] = __expf(v[j] - mx);
        s += v[j];
    }
#pragma unroll
    for (int off = 32; off > 0; off >>= 1) s += __shfl_xor(s, off);
    if ((tid & 63) == 0) reds[tid >> 6] = s;
    __syncthreads();
    s = ((reds[0] + reds[1]) + (reds[2] + reds[3])) +
        ((reds[4] + reds[5]) + (reds[6] + reds[7]));
    const float inv = 1.0f / s;
    wls[tid]       = v[0] * inv;
    wls[tid + 512] = v[1] * inv;
    __syncthreads();

    if (ds == 0) {
        attn[b * T_ + tid]       = wls[tid];
        attn[b * T_ + tid + 512] = wls[tid + 512];
    }

    const int tc = tid >> 6;        // 0..7
    const int dl = tid & 63;
    const float* fb =
        feat + ((size_t)(b * T_ + tc * 128)) * D_ + ds * 64 + dl;
    const float* wb = &wls[tc * 128];
    float acc = 0.f;
#pragma unroll 4
    for (int t = 0; t < 128; ++t)
        acc = fmaf(wb[t], fb[(size_t)t * D_], acc);
    cpart[tc][dl] = acc;
    __syncthreads();
    if (tid < 64) {
        float cs = 0.f;
#pragma unroll
        for (int k = 0; k < 8; ++k) cs += cpart[k][tid];
        ctx_out[b * D_ + ds * 64 + tid] = cs;
    }
}

extern "C" void kernel_launch(void* const* d_in, const int* in_sizes, int n_in,
                              void* d_out, int out_size, void* d_ws, size_t ws_size,
                              hipStream_t stream) {
    const float* feat   = (const float*)d_in[0];
    const float* hidden = (const float*)d_in[1];
    const float* W1w    = (const float*)d_in[2];
    const float* W1b    = (const float*)d_in[3];
    const float* W2w    = (const float*)d_in[4];
    const float* W2b    = (const float*)d_in[5];
    const float* Vw     = (const float*)d_in[6];
    // V_b cancels in softmax and doesn't affect context.

    float* out_ctx  = (float*)d_out;             // [B,D]
    float* out_attn = out_ctx + B_ * D_;         // [B,T]

    unsigned short* W1F = (unsigned short*)d_ws;             // U*D bf16 = 1 MB
    float* ph     = (float*)(W1F + (size_t)U_ * D_);         // B*U
    float* lpart  = ph + B_ * U_;                            // 8*B*T = 2 MB

    prep_kernel<<<512, 256, 0, stream>>>(W1w, hidden, W2w, W2b, W1b, W1F, ph);
    logits_mfma_kernel<<<dim3(32, B_), 512, 0, stream>>>(feat, W1F, ph, Vw,
                                                         lpart);
    ctx_kernel<<<dim3(8, B_), 512, 0, stream>>>(feat, lpart, out_attn, out_ctx);
}